// Round 5
// baseline (231.024 us; speedup 1.0000x reference)
//
#include <hip/hip_runtime.h>
#include <hip/hip_bf16.h>
#include <stdint.h>

#define B_     8
#define TT     1024
#define DIM_   2048
#define S_     512
#define H_     16
#define DH     64
#define HID    1024

typedef _Float16 half8 __attribute__((ext_vector_type(8)));
typedef _Float16 half4v __attribute__((ext_vector_type(4)));
typedef float f32x4 __attribute__((ext_vector_type(4)));

__device__ __forceinline__ void gload_lds16(const void* g, void* l) {
  __builtin_amdgcn_global_load_lds(
      (__attribute__((address_space(1))) unsigned int*)(uintptr_t)g,
      (__attribute__((address_space(3))) unsigned int*)l, 16, 0, 0);
}

// ---------------- LayerNorm + cast to fp16 ----------------
__global__ __launch_bounds__(256) void ln_cast(
    const float* __restrict__ x, const float* __restrict__ gamma,
    const float* __restrict__ beta, _Float16* __restrict__ xn)
{
  const int row = blockIdx.x;
  const int tid = threadIdx.x;
  const float* xr = x + (size_t)row * DIM_;
  float4 a = ((const float4*)xr)[tid * 2];
  float4 b = ((const float4*)xr)[tid * 2 + 1];
  float s1 = a.x + a.y + a.z + a.w + b.x + b.y + b.z + b.w;
  float s2 = a.x*a.x + a.y*a.y + a.z*a.z + a.w*a.w
           + b.x*b.x + b.y*b.y + b.z*b.z + b.w*b.w;
  #pragma unroll
  for (int d = 1; d < 64; d <<= 1) {
    s1 += __shfl_xor(s1, d, 64);
    s2 += __shfl_xor(s2, d, 64);
  }
  __shared__ float red[8];
  const int w = tid >> 6, lane = tid & 63;
  if (lane == 0) { red[w] = s1; red[4 + w] = s2; }
  __syncthreads();
  s1 = red[0] + red[1] + red[2] + red[3];
  s2 = red[4] + red[5] + red[6] + red[7];
  const float mu  = s1 * (1.0f / DIM_);
  const float var = s2 * (1.0f / DIM_) - mu * mu;
  const float rs  = rsqrtf(var + 1e-5f);
  float4 g0 = ((const float4*)gamma)[tid * 2];
  float4 g1 = ((const float4*)gamma)[tid * 2 + 1];
  float4 e0 = ((const float4*)beta)[tid * 2];
  float4 e1 = ((const float4*)beta)[tid * 2 + 1];
  half8 o;
  o[0] = (_Float16)((a.x - mu) * rs * g0.x + e0.x);
  o[1] = (_Float16)((a.y - mu) * rs * g0.y + e0.y);
  o[2] = (_Float16)((a.z - mu) * rs * g0.z + e0.z);
  o[3] = (_Float16)((a.w - mu) * rs * g0.w + e0.w);
  o[4] = (_Float16)((b.x - mu) * rs * g1.x + e1.x);
  o[5] = (_Float16)((b.y - mu) * rs * g1.y + e1.y);
  o[6] = (_Float16)((b.z - mu) * rs * g1.z + e1.z);
  o[7] = (_Float16)((b.w - mu) * rs * g1.w + e1.w);
  *(half8*)(xn + (size_t)row * DIM_ + tid * 8) = o;
}

// ---------------- elementwise f32 -> f16 cast ----------------
__global__ __launch_bounds__(256) void cast_f16(
    const float* __restrict__ in, _Float16* __restrict__ out, int n4)
{
  int i = blockIdx.x * 256 + threadIdx.x;
  if (i >= n4) return;
  float4 v = ((const float4*)in)[i];
  half4v o;
  o[0] = (_Float16)v.x; o[1] = (_Float16)v.y;
  o[2] = (_Float16)v.z; o[3] = (_Float16)v.w;
  ((half4v*)out)[i] = o;
}

// ---------------- transpose + cast: in[R][C] f32 -> out[C][R] f16 ----------------
__global__ void transpose_cast(const float* __restrict__ in,
                               _Float16* __restrict__ out, int R, int C)
{
  __shared__ float t[32][33];
  const int c0 = blockIdx.x * 32, r0 = blockIdx.y * 32;
  const int tx = threadIdx.x, ty = threadIdx.y;
  #pragma unroll
  for (int i = 0; i < 32; i += 8)
    t[ty + i][tx] = in[(size_t)(r0 + ty + i) * C + c0 + tx];
  __syncthreads();
  #pragma unroll
  for (int i = 0; i < 32; i += 8)
    out[(size_t)(c0 + ty + i) * R + r0 + tx] = (_Float16)t[tx][ty + i];
}

// ---------------- V^T builder: kv[B*S][2048] cols 1024+ -> vt[B][H][DH][S] ----------------
__global__ void build_vt(const _Float16* __restrict__ kv, _Float16* __restrict__ vt)
{
  __shared__ _Float16 t[64][65];
  const int s0 = blockIdx.x * 64;
  const int h = blockIdx.y, b = blockIdx.z;
  const int tx = threadIdx.x, ty = threadIdx.y;
  const _Float16* src = kv + (size_t)(b * S_) * 2048 + HID + h * DH;
  #pragma unroll
  for (int i = 0; i < 64; i += 8)
    t[ty + i][tx] = src[(size_t)(s0 + ty + i) * 2048 + tx];
  __syncthreads();
  _Float16* dst = vt + (size_t)((b * H_ + h) * DH) * S_;
  #pragma unroll
  for (int i = 0; i < 64; i += 8)
    dst[(size_t)(ty + i) * S_ + s0 + tx] = t[tx][ty + i];
}

// ---------------- fp16 GEMM: C[M][N] = A[M][K] @ BT[N][K]^T ----------------
template<typename OutT>
__global__ __launch_bounds__(256) void gemm_f16(
    const _Float16* __restrict__ A, const _Float16* __restrict__ BT,
    OutT* __restrict__ C, int M, int N, int K)
{
  __shared__ __align__(16) _Float16 sA[2][128 * 32];
  __shared__ __align__(16) _Float16 sB[2][128 * 32];
  const int tid = threadIdx.x;
  const int lane = tid & 63, w = tid >> 6;
  const int l15 = lane & 15, lhi = lane >> 4;
  const int wr = w >> 1, wc = w & 1;
  const int m0 = blockIdx.y * 128, n0 = blockIdx.x * 128;

  f32x4 acc[4][4] = {};

  const int rowA0 = tid >> 2,        cb0 = (tid & 3) * 8;
  const int rowA1 = (256 + tid) >> 2, cb1 = (tid & 3) * 8;

  auto stage = [&](const _Float16* __restrict__ G, _Float16* sbuf, int base, int k0) {
    gload_lds16(G + (size_t)(base + rowA0) * K + k0 + cb0, &sbuf[(w * 64) * 8]);
    gload_lds16(G + (size_t)(base + rowA1) * K + k0 + cb1, &sbuf[(256 + w * 64) * 8]);
  };

  stage(A,  sA[0], m0, 0);
  stage(BT, sB[0], n0, 0);
  __syncthreads();
  int cur = 0;
  for (int k0 = 0; k0 < K; k0 += 32) {
    const int nk = k0 + 32;
    if (nk < K) { stage(A, sA[cur ^ 1], m0, nk); stage(BT, sB[cur ^ 1], n0, nk); }
    half8 af[4], bf[4];
    #pragma unroll
    for (int m = 0; m < 4; ++m)
      af[m] = *(const half8*)&sA[cur][(wr * 64 + m * 16 + l15) * 32 + lhi * 8];
    #pragma unroll
    for (int n = 0; n < 4; ++n)
      bf[n] = *(const half8*)&sB[cur][(wc * 64 + n * 16 + l15) * 32 + lhi * 8];
    #pragma unroll
    for (int m = 0; m < 4; ++m)
      #pragma unroll
      for (int n = 0; n < 4; ++n)
        acc[m][n] = __builtin_amdgcn_mfma_f32_16x16x32_f16(af[m], bf[n], acc[m][n], 0, 0, 0);
    __syncthreads();
    cur ^= 1;
  }
  #pragma unroll
  for (int m = 0; m < 4; ++m) {
    const int row = m0 + wr * 64 + m * 16 + lhi * 4;
    #pragma unroll
    for (int n = 0; n < 4; ++n) {
      const int col = n0 + wc * 64 + n * 16 + l15;
      #pragma unroll
      for (int r = 0; r < 4; ++r)
        C[(size_t)(row + r) * N + col] = (OutT)acc[m][n][r];
    }
  }
}

// ---------------- fused attention v4: 8-wave blocks, 128 q-rows, LDS K/V ----
// Grid 1024 flat: id = tb*128 + (b*16+h); blocks sharing (b,h) are congruent
// mod 8 -> same XCD -> K/V L2-resident. 512 threads = 8 waves; wave w owns
// q-rows t0..t0+15. Per 64-s-row chunk: all 8 waves co-stage K + V^T into
// double-buffered LDS via global_load_lds(16B) with inverse-XOR-swizzled
// global source (LDS dest linear); ds_read_b128 applies the same XOR ->
// conflict-free. LDS 48KB -> 3 blocks/CU (24 waves). setprio around MFMA.
__global__ __launch_bounds__(512, 6) void attn_kernel(
    const _Float16* __restrict__ q, const _Float16* __restrict__ kv,
    const _Float16* __restrict__ vt, _Float16* __restrict__ ao)
{
  __shared__ __align__(16) _Float16 Ks[2][64 * 64];   // 8 KB each
  __shared__ __align__(16) _Float16 Vs[2][64 * 64];   // 8 KB each
  __shared__ __align__(16) _Float16 P[8][16][64];     // 16 KB
  const int tid = threadIdx.x;
  const int lane = tid & 63, w = tid >> 6;
  const int l15 = lane & 15, lhi = lane >> 4;
  const int id = blockIdx.x;
  const int bh = id & 127, tb = id >> 7;
  const int b = bh >> 4, h = bh & 15;
  const int t0 = tb * 128 + w * 16;

  const _Float16* qp = q + (size_t)(b * TT + t0 + l15) * HID + h * DH + lhi * 8;
  half8 aq0 = *(const half8*)qp;
  half8 aq1 = *(const half8*)(qp + 32);

  // staging: 1 gload per thread per buffer. Wave w covers rows w*8..w*8+7.
  // Lane l: row r = w*8 + (l>>3), LDS 16B-chunk (l&7), source chunk XOR (r&7).
  const int srow = lane >> 3;            // = r & 7
  const int sj   = (lane & 7) ^ srow;    // swizzled source 16B-chunk
  const _Float16* kbase = kv + (size_t)(b * S_) * 2048 + h * DH;
  const _Float16* vbase = vt + (size_t)((b * H_ + h) * DH) * S_;

  auto stageK = [&](int c, int pg) {
    const int r = w * 8 + srow;
    gload_lds16(kbase + (size_t)(c * 64 + r) * 2048 + sj * 8, &Ks[pg][w * 512]);
  };
  auto stageV = [&](int c, int pg) {
    const int r = w * 8 + srow;          // d-row of V^T
    gload_lds16(vbase + (size_t)r * S_ + c * 64 + sj * 8, &Vs[pg][w * 512]);
  };

  f32x4 acco[4] = {};
  float m_[4] = {-1e30f, -1e30f, -1e30f, -1e30f};
  float l_[4] = {0.f, 0.f, 0.f, 0.f};

  const int key = l15 & 7;
  const int ck0 = lhi ^ key;          // swizzled chunk for k in [lhi*8, lhi*8+8)
  const int swr = (l15 & 7) << 3;

  stageK(0, 0); stageV(0, 0);
  __syncthreads();
  int cur = 0;
  for (int c = 0; c < 8; ++c) {
    if (c + 1 < 8) { stageK(c + 1, cur ^ 1); stageV(c + 1, cur ^ 1); }
    // --- QK^T for 64 s-rows from LDS ---
    f32x4 accs[4] = {};
    __builtin_amdgcn_s_setprio(1);
    #pragma unroll
    for (int n = 0; n < 4; ++n) {
      const int row = n * 16 + l15;
      half8 kf0 = *(const half8*)&Ks[cur][row * 64 + ck0 * 8];
      half8 kf1 = *(const half8*)&Ks[cur][row * 64 + (ck0 ^ 4) * 8];
      accs[n] = __builtin_amdgcn_mfma_f32_16x16x32_f16(aq0, kf0, accs[n], 0, 0, 0);
      accs[n] = __builtin_amdgcn_mfma_f32_16x16x32_f16(aq1, kf1, accs[n], 0, 0, 0);
    }
    __builtin_amdgcn_s_setprio(0);
    // --- online softmax update (rows lhi*4+r, cols n*16+l15) ---
    #pragma unroll
    for (int r = 0; r < 4; ++r) {
      float mx = fmaxf(fmaxf(accs[0][r], accs[1][r]), fmaxf(accs[2][r], accs[3][r]));
      mx = fmaxf(mx, __shfl_xor(mx, 1, 64));
      mx = fmaxf(mx, __shfl_xor(mx, 2, 64));
      mx = fmaxf(mx, __shfl_xor(mx, 4, 64));
      mx = fmaxf(mx, __shfl_xor(mx, 8, 64));
      const float mnew = fmaxf(m_[r], mx);
      const float scale = __expf(m_[r] - mnew);
      float sm = 0.f;
      #pragma unroll
      for (int n = 0; n < 4; ++n) {
        float e = __expf(accs[n][r] - mnew);
        accs[n][r] = e;
        sm += e;
      }
      sm += __shfl_xor(sm, 1, 64);
      sm += __shfl_xor(sm, 2, 64);
      sm += __shfl_xor(sm, 4, 64);
      sm += __shfl_xor(sm, 8, 64);
      l_[r] = l_[r] * scale + sm;
      m_[r] = mnew;
      #pragma unroll
      for (int n2 = 0; n2 < 4; ++n2) acco[n2][r] *= scale;
      const int rw = lhi * 4 + r;
      const int sw = (rw & 7) << 3;
      #pragma unroll
      for (int n = 0; n < 4; ++n)
        P[w][rw][(n * 16 + l15) ^ sw] = (_Float16)accs[n][r];
    }
    // --- PV partial from LDS V^T chunk ---
    __builtin_amdgcn_s_setprio(1);
    #pragma unroll
    for (int ks = 0; ks < 2; ++ks) {
      half8 ap = *(const half8*)&P[w][l15][(ks * 32 + lhi * 8) ^ swr];
      #pragma unroll
      for (int n = 0; n < 4; ++n) {
        const int row = n * 16 + l15;
        half8 vf = *(const half8*)&Vs[cur][row * 64 + ((ks * 4 + lhi) ^ key) * 8];
        acco[n] = __builtin_amdgcn_mfma_f32_16x16x32_f16(ap, vf, acco[n], 0, 0, 0);
      }
    }
    __builtin_amdgcn_s_setprio(0);
    __syncthreads();
    cur ^= 1;
  }
  // --- finalize: /(sum * SCALE) and store ---
  _Float16* ob = ao + (size_t)(b * TT + t0 + lhi * 4) * HID + h * DH;
  #pragma unroll
  for (int r = 0; r < 4; ++r) {
    const float inv = 1.0f / (l_[r] * 8.0f);
    #pragma unroll
    for (int n = 0; n < 4; ++n)
      ob[(size_t)r * HID + n * 16 + l15] = (_Float16)(acco[n][r] * inv);
  }
}

extern "C" void kernel_launch(void* const* d_in, const int* in_sizes, int n_in,
                              void* d_out, int out_size, void* d_ws, size_t ws_size,
                              hipStream_t stream) {
  const float* x     = (const float*)d_in[0];
  const float* media = (const float*)d_in[1];
  // d_in[2] media_locations: unused (reference discards the mask)
  const float* Wq    = (const float*)d_in[3];
  const float* Wkv   = (const float*)d_in[4];
  const float* Wo    = (const float*)d_in[5];
  const float* gamma = (const float*)d_in[6];
  const float* beta  = (const float*)d_in[7];
  float* out = (float*)d_out;

  char* ws = (char*)d_ws;
  _Float16* xn     = (_Float16*)(ws);                    // 8192x2048 (32MB)
  _Float16* qh     = (_Float16*)(ws + 33554432);         // 8192x1024 (16MB)
  _Float16* kvh    = (_Float16*)(ws + 50331648);         // 4096x2048 (16MB)
  _Float16* aoh    = (_Float16*)(ws + 67108864);         // 8192x1024 (16MB)
  _Float16* vth    = (_Float16*)(ws + 83886080);         // 8x16x64x512 (8MB)
  _Float16* mediah = (_Float16*)(ws + 92274688);         // 4096x1024 (8MB)
  _Float16* wqT    = (_Float16*)(ws + 100663296);        // 1024x2048 (4MB)
  _Float16* wkvT   = (_Float16*)(ws + 104857600);        // 2048x1024 (4MB)
  _Float16* woT    = (_Float16*)(ws + 109051904);        // 2048x1024 (4MB)

  ln_cast<<<dim3(8192), dim3(256), 0, stream>>>(x, gamma, beta, xn);
  transpose_cast<<<dim3(1024/32, 2048/32), dim3(32, 8), 0, stream>>>(Wq,  wqT,  2048, 1024);
  transpose_cast<<<dim3(2048/32, 1024/32), dim3(32, 8), 0, stream>>>(Wkv, wkvT, 1024, 2048);
  transpose_cast<<<dim3(2048/32, 1024/32), dim3(32, 8), 0, stream>>>(Wo,  woT,  1024, 2048);
  cast_f16<<<dim3(4096), dim3(256), 0, stream>>>(media, mediah, 4194304 / 4);

  gemm_f16<_Float16><<<dim3(1024/128, 8192/128), dim3(256), 0, stream>>>(xn, wqT, qh, 8192, 1024, 2048);
  gemm_f16<_Float16><<<dim3(2048/128, 4096/128), dim3(256), 0, stream>>>(mediah, wkvT, kvh, 4096, 2048, 1024);
  build_vt<<<dim3(8, 16, 8), dim3(64, 8), 0, stream>>>(kvh, vth);
  attn_kernel<<<dim3(1024), dim3(512), 0, stream>>>(qh, kvh, vth, aoh);
  gemm_f16<float><<<dim3(2048/128, 8192/128), dim3(256), 0, stream>>>(aoh, woT, out, 8192, 2048, 1024);
}

// Round 6
// 210.360 us; speedup vs baseline: 1.0982x; 1.0982x over previous
//
#include <hip/hip_runtime.h>
#include <hip/hip_bf16.h>
#include <stdint.h>

#define B_     8
#define TT     1024
#define DIM_   2048
#define S_     512
#define H_     16
#define DH     64
#define HID    1024

typedef _Float16 half8 __attribute__((ext_vector_type(8)));
typedef _Float16 half4v __attribute__((ext_vector_type(4)));
typedef float f32x4 __attribute__((ext_vector_type(4)));

__device__ __forceinline__ void gload_lds16(const void* g, void* l) {
  __builtin_amdgcn_global_load_lds(
      (__attribute__((address_space(1))) unsigned int*)(uintptr_t)g,
      (__attribute__((address_space(3))) unsigned int*)l, 16, 0, 0);
}

// ---------------- LayerNorm + cast to fp16 ----------------
__global__ __launch_bounds__(256) void ln_cast(
    const float* __restrict__ x, const float* __restrict__ gamma,
    const float* __restrict__ beta, _Float16* __restrict__ xn)
{
  const int row = blockIdx.x;
  const int tid = threadIdx.x;
  const float* xr = x + (size_t)row * DIM_;
  float4 a = ((const float4*)xr)[tid * 2];
  float4 b = ((const float4*)xr)[tid * 2 + 1];
  float s1 = a.x + a.y + a.z + a.w + b.x + b.y + b.z + b.w;
  float s2 = a.x*a.x + a.y*a.y + a.z*a.z + a.w*a.w
           + b.x*b.x + b.y*b.y + b.z*b.z + b.w*b.w;
  #pragma unroll
  for (int d = 1; d < 64; d <<= 1) {
    s1 += __shfl_xor(s1, d, 64);
    s2 += __shfl_xor(s2, d, 64);
  }
  __shared__ float red[8];
  const int w = tid >> 6, lane = tid & 63;
  if (lane == 0) { red[w] = s1; red[4 + w] = s2; }
  __syncthreads();
  s1 = red[0] + red[1] + red[2] + red[3];
  s2 = red[4] + red[5] + red[6] + red[7];
  const float mu  = s1 * (1.0f / DIM_);
  const float var = s2 * (1.0f / DIM_) - mu * mu;
  const float rs  = rsqrtf(var + 1e-5f);
  float4 g0 = ((const float4*)gamma)[tid * 2];
  float4 g1 = ((const float4*)gamma)[tid * 2 + 1];
  float4 e0 = ((const float4*)beta)[tid * 2];
  float4 e1 = ((const float4*)beta)[tid * 2 + 1];
  half8 o;
  o[0] = (_Float16)((a.x - mu) * rs * g0.x + e0.x);
  o[1] = (_Float16)((a.y - mu) * rs * g0.y + e0.y);
  o[2] = (_Float16)((a.z - mu) * rs * g0.z + e0.z);
  o[3] = (_Float16)((a.w - mu) * rs * g0.w + e0.w);
  o[4] = (_Float16)((b.x - mu) * rs * g1.x + e1.x);
  o[5] = (_Float16)((b.y - mu) * rs * g1.y + e1.y);
  o[6] = (_Float16)((b.z - mu) * rs * g1.z + e1.z);
  o[7] = (_Float16)((b.w - mu) * rs * g1.w + e1.w);
  *(half8*)(xn + (size_t)row * DIM_ + tid * 8) = o;
}

// ---------------- elementwise f32 -> f16 cast ----------------
__global__ __launch_bounds__(256) void cast_f16(
    const float* __restrict__ in, _Float16* __restrict__ out, int n4)
{
  int i = blockIdx.x * 256 + threadIdx.x;
  if (i >= n4) return;
  float4 v = ((const float4*)in)[i];
  half4v o;
  o[0] = (_Float16)v.x; o[1] = (_Float16)v.y;
  o[2] = (_Float16)v.z; o[3] = (_Float16)v.w;
  ((half4v*)out)[i] = o;
}

// ---------------- transpose + cast: in[R][C] f32 -> out[C][R] f16 ----------------
__global__ void transpose_cast(const float* __restrict__ in,
                               _Float16* __restrict__ out, int R, int C)
{
  __shared__ float t[32][33];
  const int c0 = blockIdx.x * 32, r0 = blockIdx.y * 32;
  const int tx = threadIdx.x, ty = threadIdx.y;
  #pragma unroll
  for (int i = 0; i < 32; i += 8)
    t[ty + i][tx] = in[(size_t)(r0 + ty + i) * C + c0 + tx];
  __syncthreads();
  #pragma unroll
  for (int i = 0; i < 32; i += 8)
    out[(size_t)(c0 + ty + i) * R + r0 + tx] = (_Float16)t[tx][ty + i];
}

// ---------------- V^T builder: kv[B*S][2048] cols 1024+ -> vt[B][H][DH][S] ----------------
__global__ void build_vt(const _Float16* __restrict__ kv, _Float16* __restrict__ vt)
{
  __shared__ _Float16 t[64][65];
  const int s0 = blockIdx.x * 64;
  const int h = blockIdx.y, b = blockIdx.z;
  const int tx = threadIdx.x, ty = threadIdx.y;
  const _Float16* src = kv + (size_t)(b * S_) * 2048 + HID + h * DH;
  #pragma unroll
  for (int i = 0; i < 64; i += 8)
    t[ty + i][tx] = src[(size_t)(s0 + ty + i) * 2048 + tx];
  __syncthreads();
  _Float16* dst = vt + (size_t)((b * H_ + h) * DH) * S_;
  #pragma unroll
  for (int i = 0; i < 64; i += 8)
    dst[(size_t)(ty + i) * S_ + s0 + tx] = t[tx][ty + i];
}

// ---------------- fp16 GEMM: C[M][N] = A[M][K] @ BT[N][K]^T ----------------
template<typename OutT>
__global__ __launch_bounds__(256) void gemm_f16(
    const _Float16* __restrict__ A, const _Float16* __restrict__ BT,
    OutT* __restrict__ C, int M, int N, int K)
{
  __shared__ __align__(16) _Float16 sA[2][128 * 32];
  __shared__ __align__(16) _Float16 sB[2][128 * 32];
  const int tid = threadIdx.x;
  const int lane = tid & 63, w = tid >> 6;
  const int l15 = lane & 15, lhi = lane >> 4;
  const int wr = w >> 1, wc = w & 1;
  const int m0 = blockIdx.y * 128, n0 = blockIdx.x * 128;

  f32x4 acc[4][4] = {};

  const int rowA0 = tid >> 2,        cb0 = (tid & 3) * 8;
  const int rowA1 = (256 + tid) >> 2, cb1 = (tid & 3) * 8;

  auto stage = [&](const _Float16* __restrict__ G, _Float16* sbuf, int base, int k0) {
    gload_lds16(G + (size_t)(base + rowA0) * K + k0 + cb0, &sbuf[(w * 64) * 8]);
    gload_lds16(G + (size_t)(base + rowA1) * K + k0 + cb1, &sbuf[(256 + w * 64) * 8]);
  };

  stage(A,  sA[0], m0, 0);
  stage(BT, sB[0], n0, 0);
  __syncthreads();
  int cur = 0;
  for (int k0 = 0; k0 < K; k0 += 32) {
    const int nk = k0 + 32;
    if (nk < K) { stage(A, sA[cur ^ 1], m0, nk); stage(BT, sB[cur ^ 1], n0, nk); }
    half8 af[4], bf[4];
    #pragma unroll
    for (int m = 0; m < 4; ++m)
      af[m] = *(const half8*)&sA[cur][(wr * 64 + m * 16 + l15) * 32 + lhi * 8];
    #pragma unroll
    for (int n = 0; n < 4; ++n)
      bf[n] = *(const half8*)&sB[cur][(wc * 64 + n * 16 + l15) * 32 + lhi * 8];
    #pragma unroll
    for (int m = 0; m < 4; ++m)
      #pragma unroll
      for (int n = 0; n < 4; ++n)
        acc[m][n] = __builtin_amdgcn_mfma_f32_16x16x32_f16(af[m], bf[n], acc[m][n], 0, 0, 0);
    __syncthreads();
    cur ^= 1;
  }
  #pragma unroll
  for (int m = 0; m < 4; ++m) {
    const int row = m0 + wr * 64 + m * 16 + lhi * 4;
    #pragma unroll
    for (int n = 0; n < 4; ++n) {
      const int col = n0 + wc * 64 + n * 16 + l15;
      #pragma unroll
      for (int r = 0; r < 4; ++r)
        C[(size_t)(row + r) * N + col] = (OutT)acc[m][n][r];
    }
  }
}

// ---------------- fused attention v5: swapped QK^T -> lane-local softmax ----
// Grid 1024 flat: id = tb*128 + (b*16+h) (XCD-local K/V). 8 waves, wave w owns
// 16 q-rows. QK^T computed as mfma(K, Q): out row(reg)=s, col(l15)=q, so each
// lane holds 16 s-scores of the chunk for ONE q-row -> softmax = in-lane tree
// + 2 shfl_xor (16,32). P packed to half4 ds_write_b64 (XOR-swizzled). PV
// unchanged. Output routed via LDS for 16B coalesced global stores.
__global__ __launch_bounds__(512, 6) void attn_kernel(
    const _Float16* __restrict__ q, const _Float16* __restrict__ kv,
    const _Float16* __restrict__ vt, _Float16* __restrict__ ao)
{
  __shared__ __align__(16) _Float16 Ks[2][64 * 64];   // 8 KB each
  __shared__ __align__(16) _Float16 Vs[2][64 * 64];   // 8 KB each
  __shared__ __align__(16) _Float16 P[8][16 * 64];    // 16 KB (per-wave 2KB)
  const int tid = threadIdx.x;
  const int lane = tid & 63, w = tid >> 6;
  const int l15 = lane & 15, lhi = lane >> 4;
  const int id = blockIdx.x;
  const int bh = id & 127, tb = id >> 7;
  const int b = bh >> 4, h = bh & 15;
  const int t0 = tb * 128 + w * 16;

  const _Float16* qp = q + (size_t)(b * TT + t0 + l15) * HID + h * DH + lhi * 8;
  half8 aq0 = *(const half8*)qp;
  half8 aq1 = *(const half8*)(qp + 32);

  // staging: 1 gload per thread per buffer; wave w covers rows w*8..w*8+7.
  const int srow = lane >> 3;            // = r & 7
  const int sj   = (lane & 7) ^ srow;    // swizzled source 16B-chunk
  const _Float16* kbase = kv + (size_t)(b * S_) * 2048 + h * DH;
  const _Float16* vbase = vt + (size_t)((b * H_ + h) * DH) * S_;

  auto stageK = [&](int c, int pg) {
    const int r = w * 8 + srow;
    gload_lds16(kbase + (size_t)(c * 64 + r) * 2048 + sj * 8, &Ks[pg][w * 512]);
  };
  auto stageV = [&](int c, int pg) {
    const int r = w * 8 + srow;          // d-row of V^T
    gload_lds16(vbase + (size_t)r * S_ + c * 64 + sj * 8, &Vs[pg][w * 512]);
  };

  f32x4 acco[4] = {};
  float m_ = -1e30f, l_ = 0.f;           // per-lane state for q = l15

  const int key = l15 & 7;
  const int ck0 = lhi ^ key;             // swizzled chunk for k in [lhi*8,+8)
  const int swr = key << 3;

  stageK(0, 0); stageV(0, 0);
  __syncthreads();
  int cur = 0;
  for (int c = 0; c < 8; ++c) {
    if (c + 1 < 8) { stageK(c + 1, cur ^ 1); stageV(c + 1, cur ^ 1); }
    // --- QK^T swapped: accs row(reg)=s, col(l15)=q ---
    f32x4 accs[4] = {};
    __builtin_amdgcn_s_setprio(1);
    #pragma unroll
    for (int n = 0; n < 4; ++n) {
      const int row = n * 16 + l15;      // s-row fragment index
      half8 kf0 = *(const half8*)&Ks[cur][row * 64 + ck0 * 8];
      half8 kf1 = *(const half8*)&Ks[cur][row * 64 + (ck0 ^ 4) * 8];
      accs[n] = __builtin_amdgcn_mfma_f32_16x16x32_f16(kf0, aq0, accs[n], 0, 0, 0);
      accs[n] = __builtin_amdgcn_mfma_f32_16x16x32_f16(kf1, aq1, accs[n], 0, 0, 0);
    }
    __builtin_amdgcn_s_setprio(0);
    // --- lane-local online softmax for q = l15 (16 s-values in-lane) ---
    float c0 = fmaxf(fmaxf(accs[0][0], accs[0][1]), fmaxf(accs[0][2], accs[0][3]));
    float c1 = fmaxf(fmaxf(accs[1][0], accs[1][1]), fmaxf(accs[1][2], accs[1][3]));
    float c2 = fmaxf(fmaxf(accs[2][0], accs[2][1]), fmaxf(accs[2][2], accs[2][3]));
    float c3 = fmaxf(fmaxf(accs[3][0], accs[3][1]), fmaxf(accs[3][2], accs[3][3]));
    float mx = fmaxf(fmaxf(c0, c1), fmaxf(c2, c3));
    mx = fmaxf(mx, __shfl_xor(mx, 16, 64));
    mx = fmaxf(mx, __shfl_xor(mx, 32, 64));
    const float mnew = fmaxf(m_, mx);
    const float scale = __expf(m_ - mnew);
    m_ = mnew;
    float s0 = 0.f, s1 = 0.f, s2 = 0.f, s3 = 0.f;
    #pragma unroll
    for (int n = 0; n < 4; ++n) {
      #pragma unroll
      for (int r = 0; r < 4; ++r) {
        float e = __expf(accs[n][r] - mnew);
        accs[n][r] = e;
      }
    }
    s0 = (accs[0][0] + accs[0][1]) + (accs[0][2] + accs[0][3]);
    s1 = (accs[1][0] + accs[1][1]) + (accs[1][2] + accs[1][3]);
    s2 = (accs[2][0] + accs[2][1]) + (accs[2][2] + accs[2][3]);
    s3 = (accs[3][0] + accs[3][1]) + (accs[3][2] + accs[3][3]);
    float sm = (s0 + s1) + (s2 + s3);
    sm += __shfl_xor(sm, 16, 64);
    sm += __shfl_xor(sm, 32, 64);
    l_ = l_ * scale + sm;
    // --- P write: row q=l15, col s=n*16+lhi*4+r, packed half4, XOR-swizzled ---
    #pragma unroll
    for (int n = 0; n < 4; ++n) {
      half4v pw;
      pw[0] = (_Float16)accs[n][0]; pw[1] = (_Float16)accs[n][1];
      pw[2] = (_Float16)accs[n][2]; pw[3] = (_Float16)accs[n][3];
      const int base = (n * 16 + lhi * 4) ^ swr;
      *(half4v*)&P[w][l15 * 64 + base] = pw;
    }
    // --- acco rescale: factor lives at lane q; broadcast to row-layout q=lhi*4+r ---
    #pragma unroll
    for (int r = 0; r < 4; ++r) {
      const float s_r = __shfl(scale, (lane >> 4) * 4 + r, 16);
      #pragma unroll
      for (int n = 0; n < 4; ++n) acco[n][r] *= s_r;
    }
    // --- PV partial: out row(reg)=q, col(l15)=d ---
    __builtin_amdgcn_s_setprio(1);
    #pragma unroll
    for (int ks = 0; ks < 2; ++ks) {
      half8 ap = *(const half8*)&P[w][l15 * 64 + ((ks * 32 + lhi * 8) ^ swr)];
      #pragma unroll
      for (int n = 0; n < 4; ++n) {
        const int row = n * 16 + l15;
        half8 vf = *(const half8*)&Vs[cur][row * 64 + ((ks * 4 + lhi) ^ key) * 8];
        acco[n] = __builtin_amdgcn_mfma_f32_16x16x32_f16(ap, vf, acco[n], 0, 0, 0);
      }
    }
    __builtin_amdgcn_s_setprio(0);
    __syncthreads();
    cur ^= 1;
  }
  // --- finalize: scale by 1/(l*8); route through LDS for 16B coalesced stores ---
  const float inv = 1.0f / (l_ * 8.0f);        // for q = l15
  #pragma unroll
  for (int r = 0; r < 4; ++r) {
    const float inv_r = __shfl(inv, (lane >> 4) * 4 + r, 16);
    const int qrow = lhi * 4 + r;
    #pragma unroll
    for (int n = 0; n < 4; ++n) {
      const int d = n * 16 + l15;
      P[w][qrow * 64 + (d ^ (lhi << 4))] = (_Float16)(acco[n][r] * inv_r);
    }
  }
  const int q2 = lane >> 2;
  const int gbase = (((lane & 3) ^ (lane >> 4)) & 3) * 16;
  half8 o0 = *(const half8*)&P[w][q2 * 64 + gbase];
  half8 o1 = *(const half8*)&P[w][q2 * 64 + gbase + 8];
  _Float16* op = ao + (size_t)(b * TT + t0 + q2) * HID + h * DH + (lane & 3) * 16;
  *(half8*)op = o0;
  *(half8*)(op + 8) = o1;
}

extern "C" void kernel_launch(void* const* d_in, const int* in_sizes, int n_in,
                              void* d_out, int out_size, void* d_ws, size_t ws_size,
                              hipStream_t stream) {
  const float* x     = (const float*)d_in[0];
  const float* media = (const float*)d_in[1];
  // d_in[2] media_locations: unused (reference discards the mask)
  const float* Wq    = (const float*)d_in[3];
  const float* Wkv   = (const float*)d_in[4];
  const float* Wo    = (const float*)d_in[5];
  const float* gamma = (const float*)d_in[6];
  const float* beta  = (const float*)d_in[7];
  float* out = (float*)d_out;

  char* ws = (char*)d_ws;
  _Float16* xn     = (_Float16*)(ws);                    // 8192x2048 (32MB)
  _Float16* qh     = (_Float16*)(ws + 33554432);         // 8192x1024 (16MB)
  _Float16* kvh    = (_Float16*)(ws + 50331648);         // 4096x2048 (16MB)
  _Float16* aoh    = (_Float16*)(ws + 67108864);         // 8192x1024 (16MB)
  _Float16* vth    = (_Float16*)(ws + 83886080);         // 8x16x64x512 (8MB)
  _Float16* mediah = (_Float16*)(ws + 92274688);         // 4096x1024 (8MB)
  _Float16* wqT    = (_Float16*)(ws + 100663296);        // 1024x2048 (4MB)
  _Float16* wkvT   = (_Float16*)(ws + 104857600);        // 2048x1024 (4MB)
  _Float16* woT    = (_Float16*)(ws + 109051904);        // 2048x1024 (4MB)

  ln_cast<<<dim3(8192), dim3(256), 0, stream>>>(x, gamma, beta, xn);
  transpose_cast<<<dim3(1024/32, 2048/32), dim3(32, 8), 0, stream>>>(Wq,  wqT,  2048, 1024);
  transpose_cast<<<dim3(2048/32, 1024/32), dim3(32, 8), 0, stream>>>(Wkv, wkvT, 1024, 2048);
  transpose_cast<<<dim3(2048/32, 1024/32), dim3(32, 8), 0, stream>>>(Wo,  woT,  1024, 2048);
  cast_f16<<<dim3(4096), dim3(256), 0, stream>>>(media, mediah, 4194304 / 4);

  gemm_f16<_Float16><<<dim3(1024/128, 8192/128), dim3(256), 0, stream>>>(xn, wqT, qh, 8192, 1024, 2048);
  gemm_f16<_Float16><<<dim3(2048/128, 4096/128), dim3(256), 0, stream>>>(mediah, wkvT, kvh, 4096, 2048, 1024);
  build_vt<<<dim3(8, 16, 8), dim3(64, 8), 0, stream>>>(kvh, vth);
  attn_kernel<<<dim3(1024), dim3(512), 0, stream>>>(qh, kvh, vth, aoh);
  gemm_f16<float><<<dim3(2048/128, 8192/128), dim3(256), 0, stream>>>(aoh, woT, out, 8192, 2048, 1024);
}

// Round 7
// 189.824 us; speedup vs baseline: 1.2170x; 1.1082x over previous
//
#include <hip/hip_runtime.h>
#include <hip/hip_bf16.h>
#include <stdint.h>

#define B_     8
#define TT     1024
#define DIM_   2048
#define S_     512
#define H_     16
#define DH     64
#define HID    1024

typedef _Float16 half8 __attribute__((ext_vector_type(8)));
typedef _Float16 half4v __attribute__((ext_vector_type(4)));
typedef float f32x4 __attribute__((ext_vector_type(4)));

__device__ __forceinline__ void gload_lds16(const void* g, void* l) {
  __builtin_amdgcn_global_load_lds(
      (__attribute__((address_space(1))) unsigned int*)(uintptr_t)g,
      (__attribute__((address_space(3))) unsigned int*)l, 16, 0, 0);
}

// ---------------- LayerNorm + cast to fp16 ----------------
__global__ __launch_bounds__(256) void ln_cast(
    const float* __restrict__ x, const float* __restrict__ gamma,
    const float* __restrict__ beta, _Float16* __restrict__ xn)
{
  const int row = blockIdx.x;
  const int tid = threadIdx.x;
  const float* xr = x + (size_t)row * DIM_;
  float4 a = ((const float4*)xr)[tid * 2];
  float4 b = ((const float4*)xr)[tid * 2 + 1];
  float s1 = a.x + a.y + a.z + a.w + b.x + b.y + b.z + b.w;
  float s2 = a.x*a.x + a.y*a.y + a.z*a.z + a.w*a.w
           + b.x*b.x + b.y*b.y + b.z*b.z + b.w*b.w;
  #pragma unroll
  for (int d = 1; d < 64; d <<= 1) {
    s1 += __shfl_xor(s1, d, 64);
    s2 += __shfl_xor(s2, d, 64);
  }
  __shared__ float red[8];
  const int w = tid >> 6, lane = tid & 63;
  if (lane == 0) { red[w] = s1; red[4 + w] = s2; }
  __syncthreads();
  s1 = red[0] + red[1] + red[2] + red[3];
  s2 = red[4] + red[5] + red[6] + red[7];
  const float mu  = s1 * (1.0f / DIM_);
  const float var = s2 * (1.0f / DIM_) - mu * mu;
  const float rs  = rsqrtf(var + 1e-5f);
  float4 g0 = ((const float4*)gamma)[tid * 2];
  float4 g1 = ((const float4*)gamma)[tid * 2 + 1];
  float4 e0 = ((const float4*)beta)[tid * 2];
  float4 e1 = ((const float4*)beta)[tid * 2 + 1];
  half8 o;
  o[0] = (_Float16)((a.x - mu) * rs * g0.x + e0.x);
  o[1] = (_Float16)((a.y - mu) * rs * g0.y + e0.y);
  o[2] = (_Float16)((a.z - mu) * rs * g0.z + e0.z);
  o[3] = (_Float16)((a.w - mu) * rs * g0.w + e0.w);
  o[4] = (_Float16)((b.x - mu) * rs * g1.x + e1.x);
  o[5] = (_Float16)((b.y - mu) * rs * g1.y + e1.y);
  o[6] = (_Float16)((b.z - mu) * rs * g1.z + e1.z);
  o[7] = (_Float16)((b.w - mu) * rs * g1.w + e1.w);
  *(half8*)(xn + (size_t)row * DIM_ + tid * 8) = o;
}

// ---------------- elementwise f32 -> f16 cast ----------------
__global__ __launch_bounds__(256) void cast_f16(
    const float* __restrict__ in, _Float16* __restrict__ out, int n4)
{
  int i = blockIdx.x * 256 + threadIdx.x;
  if (i >= n4) return;
  float4 v = ((const float4*)in)[i];
  half4v o;
  o[0] = (_Float16)v.x; o[1] = (_Float16)v.y;
  o[2] = (_Float16)v.z; o[3] = (_Float16)v.w;
  ((half4v*)out)[i] = o;
}

// ---------------- transpose + cast: in[R][C] f32 -> out[C][R] f16 ----------------
__global__ void transpose_cast(const float* __restrict__ in,
                               _Float16* __restrict__ out, int R, int C)
{
  __shared__ float t[32][33];
  const int c0 = blockIdx.x * 32, r0 = blockIdx.y * 32;
  const int tx = threadIdx.x, ty = threadIdx.y;
  #pragma unroll
  for (int i = 0; i < 32; i += 8)
    t[ty + i][tx] = in[(size_t)(r0 + ty + i) * C + c0 + tx];
  __syncthreads();
  #pragma unroll
  for (int i = 0; i < 32; i += 8)
    out[(size_t)(c0 + ty + i) * R + r0 + tx] = (_Float16)t[tx][ty + i];
}

// ---------------- V^T builder: kv[B*S][2048] cols 1024+ -> vt[B][H][DH][S] ----------------
__global__ void build_vt(const _Float16* __restrict__ kv, _Float16* __restrict__ vt)
{
  __shared__ _Float16 t[64][65];
  const int s0 = blockIdx.x * 64;
  const int h = blockIdx.y, b = blockIdx.z;
  const int tx = threadIdx.x, ty = threadIdx.y;
  const _Float16* src = kv + (size_t)(b * S_) * 2048 + HID + h * DH;
  #pragma unroll
  for (int i = 0; i < 64; i += 8)
    t[ty + i][tx] = src[(size_t)(s0 + ty + i) * 2048 + tx];
  __syncthreads();
  _Float16* dst = vt + (size_t)((b * H_ + h) * DH) * S_;
  #pragma unroll
  for (int i = 0; i < 64; i += 8)
    dst[(size_t)(ty + i) * S_ + s0 + tx] = t[tx][ty + i];
}

// ---------------- 256x256 tile GEMM, BK=64, 8 waves, counted vmcnt ----------
// C[M][N] = A[M][K] @ BT[N][K]^T. LDS 128KB: 2 dbuf x (A 256x64 + B 256x64)
// f16, XOR-chunk-swizzled via pre-swizzled global source (attn-proven, 0
// conflicts). Raw s_barrier + s_waitcnt vmcnt(8): one full tile (8 loads/
// thread) stays in flight across the consuming barrier. 2 MFMA clusters of
// 32 per K-tile wrapped in setprio. 1 block/CU (LDS-bound).
template<int KD, int ND, typename OutT>
__device__ __forceinline__ void gemm256_body(
    const _Float16* __restrict__ A, const _Float16* __restrict__ BT,
    OutT* __restrict__ C, int m0, int n0,
    _Float16* __restrict__ sA0, _Float16* __restrict__ sA1,
    _Float16* __restrict__ sB0, _Float16* __restrict__ sB1)
{
  constexpr int NT = KD / 64;
  const int tid = threadIdx.x;
  const int lane = tid & 63, w = tid >> 6;
  const int l15 = lane & 15, lhi = lane >> 4;
  const int wr = w >> 2, wc = w & 3;          // 2 x 4 wave grid
  const int srow = lane >> 3;                 // row-in-8-group = row&7
  const int sj   = (lane & 7) ^ srow;         // pre-swizzled source chunk

  auto stageA = [&](int kt, _Float16* dst) {
    #pragma unroll
    for (int i = 0; i < 4; ++i) {
      const int r = w * 32 + i * 8 + srow;
      gload_lds16(A + (size_t)(m0 + r) * KD + kt * 64 + sj * 8,
                  dst + (w * 32 + i * 8) * 64);
    }
  };
  auto stageB = [&](int kt, _Float16* dst) {
    #pragma unroll
    for (int i = 0; i < 4; ++i) {
      const int r = w * 32 + i * 8 + srow;
      gload_lds16(BT + (size_t)(n0 + r) * KD + kt * 64 + sj * 8,
                  dst + (w * 32 + i * 8) * 64);
    }
  };

  f32x4 acc[8][4] = {};

  stageA(0, sA0); stageB(0, sB0);
  stageA(1, sA1); stageB(1, sB1);
  asm volatile("s_waitcnt vmcnt(8)" ::: "memory");   // tile0 landed
  __builtin_amdgcn_sched_barrier(0);
  __builtin_amdgcn_s_barrier();
  __builtin_amdgcn_sched_barrier(0);

  for (int kt = 0; kt < NT; ++kt) {
    _Float16* cA = (kt & 1) ? sA1 : sA0;
    _Float16* cB = (kt & 1) ? sB1 : sB0;
    #pragma unroll
    for (int h = 0; h < 2; ++h) {            // k-halves of BK=64
      half8 af[8], bf[4];
      const int ch = (h * 4 + lhi) ^ (l15 & 7);
      #pragma unroll
      for (int mf = 0; mf < 8; ++mf) {
        const int row = wr * 128 + mf * 16 + l15;
        af[mf] = *(const half8*)&cA[row * 64 + ch * 8];
      }
      #pragma unroll
      for (int nf = 0; nf < 4; ++nf) {
        const int row = wc * 64 + nf * 16 + l15;
        bf[nf] = *(const half8*)&cB[row * 64 + ch * 8];
      }
      __builtin_amdgcn_s_setprio(1);
      #pragma unroll
      for (int mf = 0; mf < 8; ++mf)
        #pragma unroll
        for (int nf = 0; nf < 4; ++nf)
          acc[mf][nf] = __builtin_amdgcn_mfma_f32_16x16x32_f16(
              af[mf], bf[nf], acc[mf][nf], 0, 0, 0);
      __builtin_amdgcn_s_setprio(0);
    }
    __builtin_amdgcn_sched_barrier(0);
    __builtin_amdgcn_s_barrier();            // all waves done reading cur buf
    __builtin_amdgcn_sched_barrier(0);
    if (kt + 2 < NT) {
      stageA(kt + 2, cA); stageB(kt + 2, cB);
      asm volatile("s_waitcnt vmcnt(8)" ::: "memory");  // tile kt+1 retired
    } else {
      asm volatile("s_waitcnt vmcnt(0)" ::: "memory");  // tail drain
    }
    __builtin_amdgcn_sched_barrier(0);
    __builtin_amdgcn_s_barrier();            // next buffer fully written
    __builtin_amdgcn_sched_barrier(0);
  }

  #pragma unroll
  for (int mf = 0; mf < 8; ++mf) {
    const int row = m0 + wr * 128 + mf * 16 + lhi * 4;
    #pragma unroll
    for (int nf = 0; nf < 4; ++nf) {
      const int col = n0 + wc * 64 + nf * 16 + l15;
      #pragma unroll
      for (int r = 0; r < 4; ++r)
        C[(size_t)(row + r) * ND + col] = (OutT)acc[mf][nf][r];
    }
  }
}

// Fused Q-proj (128 blocks) + KV-proj (128 blocks): 256 blocks = 1/CU.
// XCD-bijective: xcd = id&7; same-XCD blocks share A m-panels across all n.
__global__ __launch_bounds__(512) void gemm_qkv(
    const _Float16* __restrict__ xn, const _Float16* __restrict__ wqT,
    _Float16* __restrict__ qh,
    const _Float16* __restrict__ mediah, const _Float16* __restrict__ wkvT,
    _Float16* __restrict__ kvh)
{
  __shared__ __align__(16) _Float16 sA0[256 * 64], sA1[256 * 64];
  __shared__ __align__(16) _Float16 sB0[256 * 64], sB1[256 * 64];
  const int id = blockIdx.x;
  const int x = id & 7, k = id >> 4;
  if (((id >> 3) & 1) == 0) {
    const int n = k & 3, m = (k >> 2) * 8 + x;          // M=8192,N=1024,K=2048
    gemm256_body<2048, 1024, _Float16>(xn, wqT, qh, m * 256, n * 256,
                                       sA0, sA1, sB0, sB1);
  } else {
    const int n = k & 7, m = (k >> 3) * 8 + x;          // M=4096,N=2048,K=1024
    gemm256_body<1024, 2048, _Float16>(mediah, wkvT, kvh, m * 256, n * 256,
                                       sA0, sA1, sB0, sB1);
  }
}

// Out-proj: M=8192, N=2048, K=1024 -> 256 blocks = 1/CU, f32 out.
__global__ __launch_bounds__(512) void gemm_out(
    const _Float16* __restrict__ aoh, const _Float16* __restrict__ woT,
    float* __restrict__ out)
{
  __shared__ __align__(16) _Float16 sA0[256 * 64], sA1[256 * 64];
  __shared__ __align__(16) _Float16 sB0[256 * 64], sB1[256 * 64];
  const int id = blockIdx.x;
  const int x = id & 7, k = id >> 3;
  const int n = k & 7, m = (k >> 3) * 8 + x;
  gemm256_body<1024, 2048, float>(aoh, woT, out, m * 256, n * 256,
                                  sA0, sA1, sB0, sB1);
}

// ---------------- fused attention v6: swapped QK^T, lane-local softmax ----
// (v5 + conflict-free output staging swizzle)
__global__ __launch_bounds__(512, 6) void attn_kernel(
    const _Float16* __restrict__ q, const _Float16* __restrict__ kv,
    const _Float16* __restrict__ vt, _Float16* __restrict__ ao)
{
  __shared__ __align__(16) _Float16 Ks[2][64 * 64];   // 8 KB each
  __shared__ __align__(16) _Float16 Vs[2][64 * 64];   // 8 KB each
  __shared__ __align__(16) _Float16 P[8][16 * 64];    // 16 KB (per-wave 2KB)
  const int tid = threadIdx.x;
  const int lane = tid & 63, w = tid >> 6;
  const int l15 = lane & 15, lhi = lane >> 4;
  const int id = blockIdx.x;
  const int bh = id & 127, tb = id >> 7;
  const int b = bh >> 4, h = bh & 15;
  const int t0 = tb * 128 + w * 16;

  const _Float16* qp = q + (size_t)(b * TT + t0 + l15) * HID + h * DH + lhi * 8;
  half8 aq0 = *(const half8*)qp;
  half8 aq1 = *(const half8*)(qp + 32);

  const int srow = lane >> 3;
  const int sj   = (lane & 7) ^ srow;
  const _Float16* kbase = kv + (size_t)(b * S_) * 2048 + h * DH;
  const _Float16* vbase = vt + (size_t)((b * H_ + h) * DH) * S_;

  auto stageK = [&](int c, int pg) {
    const int r = w * 8 + srow;
    gload_lds16(kbase + (size_t)(c * 64 + r) * 2048 + sj * 8, &Ks[pg][w * 512]);
  };
  auto stageV = [&](int c, int pg) {
    const int r = w * 8 + srow;
    gload_lds16(vbase + (size_t)r * S_ + c * 64 + sj * 8, &Vs[pg][w * 512]);
  };

  f32x4 acco[4] = {};
  float m_ = -1e30f, l_ = 0.f;           // per-lane state for q = l15

  const int key = l15 & 7;
  const int ck0 = lhi ^ key;
  const int swr = key << 3;

  stageK(0, 0); stageV(0, 0);
  __syncthreads();
  int cur = 0;
  for (int c = 0; c < 8; ++c) {
    if (c + 1 < 8) { stageK(c + 1, cur ^ 1); stageV(c + 1, cur ^ 1); }
    // --- QK^T swapped: accs row(reg)=s, col(l15)=q ---
    f32x4 accs[4] = {};
    __builtin_amdgcn_s_setprio(1);
    #pragma unroll
    for (int n = 0; n < 4; ++n) {
      const int row = n * 16 + l15;
      half8 kf0 = *(const half8*)&Ks[cur][row * 64 + ck0 * 8];
      half8 kf1 = *(const half8*)&Ks[cur][row * 64 + (ck0 ^ 4) * 8];
      accs[n] = __builtin_amdgcn_mfma_f32_16x16x32_f16(kf0, aq0, accs[n], 0, 0, 0);
      accs[n] = __builtin_amdgcn_mfma_f32_16x16x32_f16(kf1, aq1, accs[n], 0, 0, 0);
    }
    __builtin_amdgcn_s_setprio(0);
    // --- lane-local online softmax for q = l15 ---
    float c0 = fmaxf(fmaxf(accs[0][0], accs[0][1]), fmaxf(accs[0][2], accs[0][3]));
    float c1 = fmaxf(fmaxf(accs[1][0], accs[1][1]), fmaxf(accs[1][2], accs[1][3]));
    float c2 = fmaxf(fmaxf(accs[2][0], accs[2][1]), fmaxf(accs[2][2], accs[2][3]));
    float c3 = fmaxf(fmaxf(accs[3][0], accs[3][1]), fmaxf(accs[3][2], accs[3][3]));
    float mx = fmaxf(fmaxf(c0, c1), fmaxf(c2, c3));
    mx = fmaxf(mx, __shfl_xor(mx, 16, 64));
    mx = fmaxf(mx, __shfl_xor(mx, 32, 64));
    const float mnew = fmaxf(m_, mx);
    const float scale = __expf(m_ - mnew);
    m_ = mnew;
    #pragma unroll
    for (int n = 0; n < 4; ++n)
      #pragma unroll
      for (int r = 0; r < 4; ++r)
        accs[n][r] = __expf(accs[n][r] - mnew);
    float s0 = (accs[0][0] + accs[0][1]) + (accs[0][2] + accs[0][3]);
    float s1 = (accs[1][0] + accs[1][1]) + (accs[1][2] + accs[1][3]);
    float s2 = (accs[2][0] + accs[2][1]) + (accs[2][2] + accs[2][3]);
    float s3 = (accs[3][0] + accs[3][1]) + (accs[3][2] + accs[3][3]);
    float sm = (s0 + s1) + (s2 + s3);
    sm += __shfl_xor(sm, 16, 64);
    sm += __shfl_xor(sm, 32, 64);
    l_ = l_ * scale + sm;
    // --- P write: row q=l15, col s=n*16+lhi*4+r, half4, XOR-swizzled ---
    #pragma unroll
    for (int n = 0; n < 4; ++n) {
      half4v pw;
      pw[0] = (_Float16)accs[n][0]; pw[1] = (_Float16)accs[n][1];
      pw[2] = (_Float16)accs[n][2]; pw[3] = (_Float16)accs[n][3];
      const int base = (n * 16 + lhi * 4) ^ swr;
      *(half4v*)&P[w][l15 * 64 + base] = pw;
    }
    // --- acco rescale (broadcast from lane q) ---
    #pragma unroll
    for (int r = 0; r < 4; ++r) {
      const float s_r = __shfl(scale, (lane >> 4) * 4 + r, 16);
      #pragma unroll
      for (int n = 0; n < 4; ++n) acco[n][r] *= s_r;
    }
    // --- PV partial ---
    __builtin_amdgcn_s_setprio(1);
    #pragma unroll
    for (int ks = 0; ks < 2; ++ks) {
      half8 ap = *(const half8*)&P[w][l15 * 64 + ((ks * 32 + lhi * 8) ^ swr)];
      #pragma unroll
      for (int n = 0; n < 4; ++n) {
        const int row = n * 16 + l15;
        half8 vf = *(const half8*)&Vs[cur][row * 64 + ((ks * 4 + lhi) ^ key) * 8];
        acco[n] = __builtin_amdgcn_mfma_f32_16x16x32_f16(ap, vf, acco[n], 0, 0, 0);
      }
    }
    __builtin_amdgcn_s_setprio(0);
    __syncthreads();
    cur ^= 1;
  }
  // --- finalize: chunk-XOR staging (conflict-free read-back) ---
  const float inv = 1.0f / (l_ * 8.0f);
  #pragma unroll
  for (int r = 0; r < 4; ++r) {
    const float inv_r = __shfl(inv, (lane >> 4) * 4 + r, 16);
    const int qrow = lhi * 4 + r;
    const int kq = qrow & 7;
    #pragma unroll
    for (int n = 0; n < 4; ++n) {
      const int d = n * 16 + l15;
      P[w][qrow * 64 + (((d >> 3) ^ kq) * 8) + (d & 7)] =
          (_Float16)(acco[n][r] * inv_r);
    }
  }
  const int q2 = lane >> 2;
  const int kq2 = q2 & 7;
  const int g0 = ((lane & 3) * 2) ^ kq2;
  const int g1 = ((lane & 3) * 2 + 1) ^ kq2;
  half8 o0 = *(const half8*)&P[w][q2 * 64 + g0 * 8];
  half8 o1 = *(const half8*)&P[w][q2 * 64 + g1 * 8];
  _Float16* op = ao + (size_t)(b * TT + t0 + q2) * HID + h * DH + (lane & 3) * 16;
  *(half8*)op = o0;
  *(half8*)(op + 8) = o1;
}

extern "C" void kernel_launch(void* const* d_in, const int* in_sizes, int n_in,
                              void* d_out, int out_size, void* d_ws, size_t ws_size,
                              hipStream_t stream) {
  const float* x     = (const float*)d_in[0];
  const float* media = (const float*)d_in[1];
  // d_in[2] media_locations: unused (reference discards the mask)
  const float* Wq    = (const float*)d_in[3];
  const float* Wkv   = (const float*)d_in[4];
  const float* Wo    = (const float*)d_in[5];
  const float* gamma = (const float*)d_in[6];
  const float* beta  = (const float*)d_in[7];
  float* out = (float*)d_out;

  char* ws = (char*)d_ws;
  _Float16* xn     = (_Float16*)(ws);                    // 8192x2048 (32MB)
  _Float16* qh     = (_Float16*)(ws + 33554432);         // 8192x1024 (16MB)
  _Float16* kvh    = (_Float16*)(ws + 50331648);         // 4096x2048 (16MB)
  _Float16* aoh    = (_Float16*)(ws + 67108864);         // 8192x1024 (16MB)
  _Float16* vth    = (_Float16*)(ws + 83886080);         // 8x16x64x512 (8MB)
  _Float16* mediah = (_Float16*)(ws + 92274688);         // 4096x1024 (8MB)
  _Float16* wqT    = (_Float16*)(ws + 100663296);        // 1024x2048 (4MB)
  _Float16* wkvT   = (_Float16*)(ws + 104857600);        // 2048x1024 (4MB)
  _Float16* woT    = (_Float16*)(ws + 109051904);        // 2048x1024 (4MB)

  ln_cast<<<dim3(8192), dim3(256), 0, stream>>>(x, gamma, beta, xn);
  transpose_cast<<<dim3(1024/32, 2048/32), dim3(32, 8), 0, stream>>>(Wq,  wqT,  2048, 1024);
  transpose_cast<<<dim3(2048/32, 1024/32), dim3(32, 8), 0, stream>>>(Wkv, wkvT, 1024, 2048);
  transpose_cast<<<dim3(2048/32, 1024/32), dim3(32, 8), 0, stream>>>(Wo,  woT,  1024, 2048);
  cast_f16<<<dim3(4096), dim3(256), 0, stream>>>(media, mediah, 4194304 / 4);

  gemm_qkv<<<dim3(256), dim3(512), 0, stream>>>(xn, wqT, qh, mediah, wkvT, kvh);
  build_vt<<<dim3(8, 16, 8), dim3(64, 8), 0, stream>>>(kvh, vth);
  attn_kernel<<<dim3(1024), dim3(512), 0, stream>>>(qh, kvh, vth, aoh);
  gemm_out<<<dim3(256), dim3(512), 0, stream>>>(aoh, woT, out);
}